// Round 6
// baseline (171.062 us; speedup 1.0000x reference)
//
#include <hip/hip_runtime.h>
#include <hip/hip_bf16.h>
#include <stdint.h>

#define PHh 16
#define PWw 16
#define Bn  32
#define Cn  3
#define Hn  512
#define Wn  512
#define Nn  196
#define Dn  768
#define Kn  768            // C*PH*PW
#define Mn  (Bn * Nn)      // 6272
#define NT  (Kn / 32)      // 24 K-steps

typedef __attribute__((ext_vector_type(8))) short   short8;
typedef __attribute__((ext_vector_type(4))) float   f32x4;

// ---------------------------------------------------------------------------
// Kernel 1: Wt[d][k] = bf16(W[k][d])  (LDS-tiled transpose, 32x32 tiles)
// ---------------------------------------------------------------------------
__global__ void transpose_w(const float* __restrict__ W,
                            __hip_bfloat16* __restrict__ Wt) {
    __shared__ float tile[32][33];
    int d0 = blockIdx.x * 32;
    int k0 = blockIdx.y * 32;
    int lx = threadIdx.x & 31;
    int ly = threadIdx.x >> 5;     // 0..7
#pragma unroll
    for (int i = 0; i < 4; ++i) {
        int kk = ly + i * 8;
        tile[kk][lx] = W[(size_t)(k0 + kk) * Dn + d0 + lx];
    }
    __syncthreads();
#pragma unroll
    for (int i = 0; i < 4; ++i) {
        int dd = ly + i * 8;
        Wt[(size_t)(d0 + dd) * Kn + k0 + lx] = __float2bfloat16(tile[lx][dd]);
    }
}

// ---------------------------------------------------------------------------
// Kernel 2 (fused, 2-phase pipelined): gather->bf16 A in LDS, B via
// global_load_lds from Wt, double-buffered LDS, ONE barrier per K-step.
// BM=64, BN=128, BK=32; grid 98x6=588 blocks; 4 waves (2x2); LB(256,4).
// Iter t: write A(t+1) from regs, issue B-stage(t+1), issue px loads(t+2),
// then ds_read+MFMA from buf[cur]. Stage latency hides under compute.
// ---------------------------------------------------------------------------
__device__ __forceinline__ void gload_lds16(const __hip_bfloat16* g,
                                            __hip_bfloat16* l) {
    __builtin_amdgcn_global_load_lds(
        (const __attribute__((address_space(1))) void*)g,
        (__attribute__((address_space(3))) void*)l, 16, 0, 0);
}

__global__ __launch_bounds__(256, 4) void fused_patch_gemm(
    const float* __restrict__ x,
    const int* __restrict__ centers,
    const __hip_bfloat16* __restrict__ Bt,
    const float* __restrict__ bias,
    float* __restrict__ C) {
    __shared__ __hip_bfloat16 As[2][64 * 32];     //  8 KiB
    __shared__ __hip_bfloat16 Bs[2][128 * 32];    // 16 KiB

    const int bm = blockIdx.x;       // 0..97
    const int bn = blockIdx.y;       // 0..5
    const int tid = threadIdx.x;
    const int w = tid >> 6;          // wave 0..3
    const int l = tid & 63;
    const int wr = w >> 1;           // wave row 0..1  (32 rows each)
    const int wc = w & 1;            // wave col 0..1  (64 cols each)

    // ---- A-gather role: thread = (row ml, quarter q); 8 px per step
    const int ml = tid >> 2;         // 0..63
    const int q  = tid & 3;          // 0..3
    const int m  = bm * 64 + ml;
    const int b  = m / Nn;
    const int2 cc = *reinterpret_cast<const int2*>(centers + 2 * m);
    const int sh = min(max(cc.x - PHh / 2, 0), Hn - PHh);
    const int sw = min(max(cc.y - PWw / 2, 0), Wn - PWw);
    const float* xbase = x + ((size_t)(b * Cn) * Hn + sh) * Wn + sw;

    // ---- B staging: lane covers 16B of one Wt row
    const int srow = w * 16 + (l >> 2);      // 0..63
    const int skk  = (l & 3) * 8;
    const __hip_bfloat16* Bg0 = Bt + (size_t)(bn * 128 + srow) * Kn + skk;

    // ---- fragment addressing
    const int fr = l & 15;
    const int fq = l >> 4;

    f32x4 acc[2][4] = {};

    auto srcAt = [&](int t) -> const float* {
        int k0 = t * 32 + q * 8;
        int c  = k0 >> 8;
        int ph = (k0 >> 4) & 15;
        int pw = k0 & 15;
        return xbase + ((size_t)c * Hn + ph) * Wn + pw;
    };
    auto stageB = [&](int bi, int t) {
        const __hip_bfloat16* g = Bg0 + t * 32;
        gload_lds16(g,           &Bs[bi][w * 512]);
        gload_lds16(g + 64 * Kn, &Bs[bi][2048 + w * 512]);
    };
    auto writeA = [&](int bi, float4 lo, float4 hi) {
        __hip_bfloat16 v[8];
        v[0] = __float2bfloat16(lo.x); v[1] = __float2bfloat16(lo.y);
        v[2] = __float2bfloat16(lo.z); v[3] = __float2bfloat16(lo.w);
        v[4] = __float2bfloat16(hi.x); v[5] = __float2bfloat16(hi.y);
        v[6] = __float2bfloat16(hi.z); v[7] = __float2bfloat16(hi.w);
        *reinterpret_cast<short8*>(&As[bi][tid * 8]) =
            *reinterpret_cast<const short8*>(v);
    };

    // prologue: buffer 0 <- step 0; register pipe <- step 1
    stageB(0, 0);
    {
        const float* s0 = srcAt(0);
        float4 lo = *reinterpret_cast<const float4*>(s0);
        float4 hi = *reinterpret_cast<const float4*>(s0 + 4);
        writeA(0, lo, hi);
    }
    const float* s1 = srcAt(1);
    float4 plo = *reinterpret_cast<const float4*>(s1);
    float4 phi = *reinterpret_cast<const float4*>(s1 + 4);
    __syncthreads();                 // buf0 ready (drains gload + ds_write)

    int cur = 0;
    for (int t = 0; t < NT; ++t) {
        // ---- stage step t+1 into buf[cur^1] (block-uniform guard)
        if (t + 1 < NT) {
            writeA(cur ^ 1, plo, phi);       // px(t+1), loaded last iter
            stageB(cur ^ 1, t + 1);          // flies under MFMA below
            if (t + 2 < NT) {
                const float* sn = srcAt(t + 2);
                plo = *reinterpret_cast<const float4*>(sn);
                phi = *reinterpret_cast<const float4*>(sn + 4);
            }
        }

        // ---- compute from buf[cur]
        short8 af[2], bfrag[4];
#pragma unroll
        for (int mm = 0; mm < 2; ++mm)
            af[mm] = *reinterpret_cast<const short8*>(
                &As[cur][(wr * 32 + mm * 16 + fr) * 32 + fq * 8]);
#pragma unroll
        for (int n = 0; n < 4; ++n)
            bfrag[n] = *reinterpret_cast<const short8*>(
                &Bs[cur][(wc * 64 + n * 16 + fr) * 32 + fq * 8]);
#pragma unroll
        for (int mm = 0; mm < 2; ++mm)
#pragma unroll
            for (int n = 0; n < 4; ++n)
                acc[mm][n] = __builtin_amdgcn_mfma_f32_16x16x32_bf16(
                    af[mm], bfrag[n], acc[mm][n], 0, 0, 0);

        __syncthreads();             // single barrier: buf[cur^1] now ready,
        cur ^= 1;                    // buf[cur] free to overwrite next iter
    }

    // epilogue: C/D layout col=lane&15, row=(lane>>4)*4+j
#pragma unroll
    for (int n = 0; n < 4; ++n) {
        int col = bn * 128 + wc * 64 + n * 16 + fr;
        float bv = bias[col];
#pragma unroll
        for (int mm = 0; mm < 2; ++mm) {
            int row0 = bm * 64 + wr * 32 + mm * 16 + fq * 4;
#pragma unroll
            for (int j = 0; j < 4; ++j)
                C[(size_t)(row0 + j) * Dn + col] = acc[mm][n][j] + bv;
        }
    }
}

// ---------------------------------------------------------------------------
// Fallback (ws too small): naive fp32, one thread per output element
// ---------------------------------------------------------------------------
__global__ void naive_patch_embed(const float* __restrict__ x,
                                  const int* __restrict__ centers,
                                  const float* __restrict__ W,
                                  const float* __restrict__ bias,
                                  float* __restrict__ out) {
    int idx = blockIdx.x * blockDim.x + threadIdx.x;
    if (idx >= Mn * Dn) return;
    int m = idx / Dn;
    int d = idx - m * Dn;
    int b = m / Nn;
    int ch = centers[m * 2 + 0];
    int cw = centers[m * 2 + 1];
    int sh = min(max(ch - 8, 0), Hn - PHh);
    int sw = min(max(cw - 8, 0), Wn - PWw);
    float accv = bias[d];
    for (int c = 0; c < Cn; ++c)
        for (int ph = 0; ph < PHh; ++ph) {
            const float* row = x + ((size_t)(b * Cn + c) * Hn + sh + ph) * Wn + sw;
            const float* wr = W + (size_t)(c * 256 + ph * 16) * Dn + d;
#pragma unroll
            for (int pw = 0; pw < PWw; ++pw)
                accv += row[pw] * wr[(size_t)pw * Dn];
        }
    out[idx] = accv;
}

// ---------------------------------------------------------------------------
extern "C" void kernel_launch(void* const* d_in, const int* in_sizes, int n_in,
                              void* d_out, int out_size, void* d_ws, size_t ws_size,
                              hipStream_t stream) {
    const float* x       = (const float*)d_in[0];
    const int*   centers = (const int*)d_in[1];
    const float* W       = (const float*)d_in[2];
    const float* bias    = (const float*)d_in[3];
    float*       out     = (float*)d_out;

    const size_t needW = (size_t)Kn * Dn * sizeof(__hip_bfloat16);  // 1,179,648

    if (ws_size >= needW) {
        __hip_bfloat16* Wt = (__hip_bfloat16*)d_ws;

        dim3 g2(Dn / 32, Kn / 32);
        transpose_w<<<g2, 256, 0, stream>>>(W, Wt);

        dim3 g3(Mn / 64, Dn / 128);           // 98 x 6 = 588 blocks
        fused_patch_gemm<<<g3, 256, 0, stream>>>(x, centers, Wt, bias, out);
    } else {
        int g = (Mn * Dn + 255) / 256;
        naive_patch_embed<<<g, 256, 0, stream>>>(x, centers, W, bias, out);
    }
}

// Round 7
// 166.137 us; speedup vs baseline: 1.0296x; 1.0296x over previous
//
#include <hip/hip_runtime.h>
#include <hip/hip_bf16.h>
#include <stdint.h>

#define PHh 16
#define PWw 16
#define Bn  32
#define Cn  3
#define Hn  512
#define Wn  512
#define Nn  196
#define Dn  768
#define Kn  768            // C*PH*PW
#define Mn  (Bn * Nn)      // 6272

typedef __attribute__((ext_vector_type(8))) short   short8;
typedef __attribute__((ext_vector_type(4))) float   f32x4;

// ---------------------------------------------------------------------------
// Kernel 1: Wt[d][k] = bf16(W[k][d])  (LDS-tiled transpose, 32x32 tiles)
// ---------------------------------------------------------------------------
__global__ void transpose_w(const float* __restrict__ W,
                            __hip_bfloat16* __restrict__ Wt) {
    __shared__ float tile[32][33];
    int d0 = blockIdx.x * 32;
    int k0 = blockIdx.y * 32;
    int lx = threadIdx.x & 31;
    int ly = threadIdx.x >> 5;     // 0..7
#pragma unroll
    for (int i = 0; i < 4; ++i) {
        int kk = ly + i * 8;
        tile[kk][lx] = W[(size_t)(k0 + kk) * Dn + d0 + lx];
    }
    __syncthreads();
#pragma unroll
    for (int i = 0; i < 4; ++i) {
        int dd = ly + i * 8;
        Wt[(size_t)(d0 + dd) * Kn + k0 + lx] = __float2bfloat16(tile[lx][dd]);
    }
}

// ---------------------------------------------------------------------------
// Kernel 2 (fused): gather patches from x -> bf16 LDS A-tile, B via
// global_load_lds from Wt, MFMA, bias, store. BM=64, BN=128, BK=32.
// Grid 98x6 = 588 blocks, 4 waves (2x2), LB(256,4).
// Best-measured configuration (round 5: 165.7 us).
// ---------------------------------------------------------------------------
__device__ __forceinline__ void gload_lds16(const __hip_bfloat16* g,
                                            __hip_bfloat16* l) {
    __builtin_amdgcn_global_load_lds(
        (const __attribute__((address_space(1))) void*)g,
        (__attribute__((address_space(3))) void*)l, 16, 0, 0);
}

__global__ __launch_bounds__(256, 4) void fused_patch_gemm(
    const float* __restrict__ x,
    const int* __restrict__ centers,
    const __hip_bfloat16* __restrict__ Bt,
    const float* __restrict__ bias,
    float* __restrict__ C) {
    __shared__ __hip_bfloat16 As[64 * 32];    // 4 KiB
    __shared__ __hip_bfloat16 Bs[128 * 32];   // 8 KiB

    const int bm = blockIdx.x;       // 0..97  (row tiles of 64)
    const int bn = blockIdx.y;       // 0..5   (col tiles of 128)
    const int tid = threadIdx.x;
    const int w = tid >> 6;          // wave 0..3
    const int l = tid & 63;
    const int wr = w >> 1;           // wave row 0..1  (32 rows each)
    const int wc = w & 1;            // wave col 0..1  (64 cols each)

    // ---- A-gather role: thread = (row ml, quarter q); 8 px per thread/step
    const int ml = tid >> 2;         // 0..63 : patch row within tile
    const int q  = tid & 3;          // 0..3  : 8-elem quarter of the 32-k step
    const int m  = bm * 64 + ml;     // global patch index
    const int b  = m / Nn;
    const int2 cc = *reinterpret_cast<const int2*>(centers + 2 * m);
    const int sh = min(max(cc.x - PHh / 2, 0), Hn - PHh);
    const int sw = min(max(cc.y - PWw / 2, 0), Wn - PWw);
    const float* xbase = x + ((size_t)(b * Cn) * Hn + sh) * Wn + sw;
    // LDS dest: ml*32 + q*8 == tid*8  -> linear 16B/thread, conflict-free
    __hip_bfloat16* adst = As + tid * 8;

    // ---- B staging (global_load_lds, linear LDS): lane covers 16B of a row
    const int srow = w * 16 + (l >> 2);      // 0..63
    const int skk  = (l & 3) * 8;
    const __hip_bfloat16* Bg = Bt + (size_t)(bn * 128 + srow) * Kn + skk;

    // ---- fragment addressing
    const int fr = l & 15;           // row (A) / col (B) within 16
    const int fq = l >> 4;           // k-chunk 0..3

    f32x4 acc[2][4] = {};

    // pixel source for K-step t (k0 = t*32 + q*8):
    //   c = k0>>8, ph = (k0>>4)&15, pw = k0&15 (0 or 8)
    auto srcAt = [&](int t) -> const float* {
        int k0 = t * 32 + q * 8;
        int c  = k0 >> 8;
        int ph = (k0 >> 4) & 15;
        int pw = k0 & 15;
        return xbase + ((size_t)c * Hn + ph) * Wn + pw;
    };

    // prologue: preload pixels for t=0
    const float* s0 = srcAt(0);
    float4 lo = *reinterpret_cast<const float4*>(s0);
    float4 hi = *reinterpret_cast<const float4*>(s0 + 4);

    for (int t = 0; t < Kn / 32; ++t) {
        // issue B staging for this step (stays in flight until barrier)
        gload_lds16(Bg,           Bs + w * 512);          // B rows 0..63
        gload_lds16(Bg + 64 * Kn, Bs + 2048 + w * 512);   // B rows 64..127
        Bg += 32;

        // convert current pixels -> bf16, write A subtile (ds_write_b128)
        __hip_bfloat16 v[8];
        v[0] = __float2bfloat16(lo.x); v[1] = __float2bfloat16(lo.y);
        v[2] = __float2bfloat16(lo.z); v[3] = __float2bfloat16(lo.w);
        v[4] = __float2bfloat16(hi.x); v[5] = __float2bfloat16(hi.y);
        v[6] = __float2bfloat16(hi.z); v[7] = __float2bfloat16(hi.w);
        *reinterpret_cast<short8*>(adst) = *reinterpret_cast<const short8*>(v);

        // T14 issue-early: next step's pixel loads fly during MFMA phase
        const float* sn = srcAt(t < Kn / 32 - 1 ? t + 1 : 0);
        float4 nlo = *reinterpret_cast<const float4*>(sn);
        float4 nhi = *reinterpret_cast<const float4*>(sn + 4);

        __syncthreads();              // drains A ds_write + B gload

        short8 af[2], bfrag[4];
#pragma unroll
        for (int mm = 0; mm < 2; ++mm)
            af[mm] = *reinterpret_cast<const short8*>(
                &As[(wr * 32 + mm * 16 + fr) * 32 + fq * 8]);
#pragma unroll
        for (int n = 0; n < 4; ++n)
            bfrag[n] = *reinterpret_cast<const short8*>(
                &Bs[(wc * 64 + n * 16 + fr) * 32 + fq * 8]);
#pragma unroll
        for (int mm = 0; mm < 2; ++mm)
#pragma unroll
            for (int n = 0; n < 4; ++n)
                acc[mm][n] = __builtin_amdgcn_mfma_f32_16x16x32_bf16(
                    af[mm], bfrag[n], acc[mm][n], 0, 0, 0);
        __syncthreads();

        lo = nlo; hi = nhi;
    }

    // epilogue: C/D layout col=lane&15, row=(lane>>4)*4+j
#pragma unroll
    for (int n = 0; n < 4; ++n) {
        int col = bn * 128 + wc * 64 + n * 16 + fr;
        float bv = bias[col];
#pragma unroll
        for (int mm = 0; mm < 2; ++mm) {
            int row0 = bm * 64 + wr * 32 + mm * 16 + fq * 4;
#pragma unroll
            for (int j = 0; j < 4; ++j)
                C[(size_t)(row0 + j) * Dn + col] = acc[mm][n][j] + bv;
        }
    }
}

// ---------------------------------------------------------------------------
// Fallback (ws too small): naive fp32, one thread per output element
// ---------------------------------------------------------------------------
__global__ void naive_patch_embed(const float* __restrict__ x,
                                  const int* __restrict__ centers,
                                  const float* __restrict__ W,
                                  const float* __restrict__ bias,
                                  float* __restrict__ out) {
    int idx = blockIdx.x * blockDim.x + threadIdx.x;
    if (idx >= Mn * Dn) return;
    int m = idx / Dn;
    int d = idx - m * Dn;
    int b = m / Nn;
    int ch = centers[m * 2 + 0];
    int cw = centers[m * 2 + 1];
    int sh = min(max(ch - 8, 0), Hn - PHh);
    int sw = min(max(cw - 8, 0), Wn - PWw);
    float accv = bias[d];
    for (int c = 0; c < Cn; ++c)
        for (int ph = 0; ph < PHh; ++ph) {
            const float* row = x + ((size_t)(b * Cn + c) * Hn + sh + ph) * Wn + sw;
            const float* wr = W + (size_t)(c * 256 + ph * 16) * Dn + d;
#pragma unroll
            for (int pw = 0; pw < PWw; ++pw)
                accv += row[pw] * wr[(size_t)pw * Dn];
        }
    out[idx] = accv;
}

// ---------------------------------------------------------------------------
extern "C" void kernel_launch(void* const* d_in, const int* in_sizes, int n_in,
                              void* d_out, int out_size, void* d_ws, size_t ws_size,
                              hipStream_t stream) {
    const float* x       = (const float*)d_in[0];
    const int*   centers = (const int*)d_in[1];
    const float* W       = (const float*)d_in[2];
    const float* bias    = (const float*)d_in[3];
    float*       out     = (float*)d_out;

    const size_t needW = (size_t)Kn * Dn * sizeof(__hip_bfloat16);  // 1,179,648

    if (ws_size >= needW) {
        __hip_bfloat16* Wt = (__hip_bfloat16*)d_ws;

        dim3 g2(Dn / 32, Kn / 32);
        transpose_w<<<g2, 256, 0, stream>>>(W, Wt);

        dim3 g3(Mn / 64, Dn / 128);           // 98 x 6 = 588 blocks
        fused_patch_gemm<<<g3, 256, 0, stream>>>(x, centers, Wt, bias, out);
    } else {
        int g = (Mn * Dn + 255) / 256;
        naive_patch_embed<<<g, 256, 0, stream>>>(x, centers, W, bias, out);
    }
}